// Round 8
// baseline (6789.584 us; speedup 1.0000x reference)
//
#include <hip/hip_runtime.h>
#include <math.h>

#define B_   2048
#define T_   100
#define V_   20000
#define VP   20480
#define KP   128
#define TP   112
#define NC2  64    // v-chunks (320 v each): 1024 blocks -> 4 blocks/CU available
#define CH2  320
#define LDV  72    // vv LDS row stride (shorts): 144B = 16B-aligned, 2-way banks (free)
#define RXB  158   // k_rec v-split blocks (128 v each)

typedef short s8v __attribute__((ext_vector_type(8)));
typedef short s4v __attribute__((ext_vector_type(4)));
typedef float f4  __attribute__((ext_vector_type(4)));

__device__ __forceinline__ short f2bf(float f) {
    unsigned u = __builtin_bit_cast(unsigned, f);
    u += 0x7fffu + ((u >> 16) & 1u);
    return (short)(u >> 16);
}
__device__ __forceinline__ float bf2f(short h) {
    unsigned u = ((unsigned)(unsigned short)h) << 16;
    return __builtin_bit_cast(float, u);
}
#define MFMA(a,b,c) __builtin_amdgcn_mfma_f32_16x16x32_bf16((a),(b),(c),0,0,0)

// A1[v][t] = exp(-lam*M[t][v]) bf16 (t-pad to 128, v-pad to VP, zeros)
// W1[v][t] = 1 - M[t][v] bf16 (same pads)
__global__ void k_initKT(const float* __restrict__ M, const int* __restrict__ alpha,
                         short* __restrict__ A1, short* __restrict__ W1) {
    __shared__ float tile[32][33];
    float lam = (float)(*alpha);
    int v0 = blockIdx.x * 32, t0 = blockIdx.y * 32;
    int tx = threadIdx.x, ty = threadIdx.y;
    for (int j = 0; j < 4; ++j) {
        int t = t0 + ty + 8 * j, v = v0 + tx;
        tile[ty + 8 * j][tx] = (t < T_ && v < V_) ? M[(size_t)t * V_ + v] : 0.f;
    }
    __syncthreads();
    for (int j = 0; j < 4; ++j) {
        int t = t0 + tx, v = v0 + ty + 8 * j;
        float m = tile[tx][ty + 8 * j];
        bool valid = (t < T_) && (v < V_);
        A1[(size_t)v * KP + t] = valid ? f2bf(__expf(-m * lam)) : (short)0;
        W1[(size_t)v * KP + t] = valid ? f2bf(1.f - m) : (short)0;
    }
}

// A2[t][v] = K bf16, A2M[t][v] = K*M bf16; [TP][VP] zero-padded
__global__ void k_initA2(const float* __restrict__ M, const int* __restrict__ alpha,
                         short* __restrict__ A2, short* __restrict__ A2M) {
    float lam = (float)(*alpha);
    size_t id = (size_t)blockIdx.x * 256 + threadIdx.x;   // < TP*VP
    int t = (int)(id / VP), v = (int)(id % VP);
    bool valid = (t < T_) && (v < V_);
    float m = valid ? M[(size_t)t * V_ + v] : 0.f;
    float k = valid ? __expf(-m * lam) : 0.f;
    A2[id]  = valid ? f2bf(k) : (short)0;
    A2M[id] = valid ? f2bf(k * m) : (short)0;
}

// uT init (1/T in bf16, pads zero)
__global__ void k_init0(short* __restrict__ uTbf) {
    int id = blockIdx.x * 256 + threadIdx.x;   // < B_*KP
    int t = id & (KP - 1);
    uTbf[id] = (t < T_) ? f2bf(0.01f) : (short)0;
}

// dwbf[b][v] = bf16(dw[b][v]) flat; nt (write-once stream)
__global__ void k_castdw(const float* __restrict__ dw, short* __restrict__ dwbf) {
    size_t base = ((size_t)blockIdx.x * 256 + threadIdx.x) * 8;   // < B_*V_
    f4 x0 = __builtin_nontemporal_load((const f4*)(dw + base));
    f4 x1 = __builtin_nontemporal_load((const f4*)(dw + base + 4));
    s8v o;
    o[0]=f2bf(x0[0]); o[1]=f2bf(x0[1]); o[2]=f2bf(x0[2]); o[3]=f2bf(x0[3]);
    o[4]=f2bf(x1[0]); o[5]=f2bf(x1[1]); o[6]=f2bf(x1[2]); o[7]=f2bf(x1[3]);
    __builtin_nontemporal_store(o, (s8v*)(dwbf + base));
}

// dtbf[b][t] bf16, t-pad 128
__global__ void k_castdt(const float* __restrict__ dt, short* __restrict__ dtbf) {
    int id = blockIdx.x * 256 + threadIdx.x;   // < B_*KP
    int b = id >> 7, t = id & (KP - 1);
    dtbf[id] = (t < T_) ? f2bf(dt[(size_t)b * T_ + t]) : (short)0;
}

// Fused Sinkhorn iteration kernel — free-running waves, occupancy-oriented:
//   k_GF is latency-bound with MLP*TLP too small; grid=512 capped residency at
//   2 blocks/CU. Now NC2=64 chunks of 320 v (5 strips) -> 1024 blocks -> 3
//   blocks/CU available (launch_bounds(256,3)), waves free-running (no
//   barriers). Prefetch arrays (dwn/a2r) dropped: measured ~0 and their VGPRs
//   would cap occupancy. Operand traffic per MFMA unchanged (cb=2, 128-b
//   blocks). part2 stores stay nt (write-once stream).
//   blockIdx swizzled: XCD (l%8) owns chunks 8x..8x+7 (A-slices ~1.2MB fit L2).
__global__ __launch_bounds__(256, 3) void k_GF(const short* __restrict__ A1,
                                               const short* __restrict__ A2acc,
                                               const short* __restrict__ uT,
                                               const short* __restrict__ dwbf,
                                               float* __restrict__ part2) {
    __shared__ short vv[4][32 * LDV];
    int tid = threadIdx.x;
    int wave = tid >> 6, lane = tid & 63, q = lane >> 4, l16 = lane & 15;

    // bijective swizzle: l -> (bx, c); XCD (l%8) -> chunks 8x..8x+7
    int l = blockIdx.x;
    int j = l & 63, bx = l >> 6;
    int c = ((j & 7) << 3) | (j >> 3);
    int v0 = c * CH2;
    int b0 = bx * 128 + wave * 32;     // wave's 32 b
    short* buf = vv[wave];             // wave-private LDS region

    // hoisted uT B-frags (lane n=l16 -> b; k = ks*32 + q*8 + j), strip-invariant
    s8v au[2][4];
#pragma unroll
    for (int cb = 0; cb < 2; ++cb)
#pragma unroll
        for (int ks = 0; ks < 4; ++ks)
            au[cb][ks] = *(const s8v*)(uT + (size_t)(b0 + cb * 16 + l16) * KP + ks * 32 + q * 8);

    f4 acc2[7][2];
#pragma unroll
    for (int tt = 0; tt < 7; ++tt) { acc2[tt][0] = (f4)0.f; acc2[tt][1] = (f4)0.f; }

    for (int s = 0; s < 5; ++s) {
        int vs = v0 + s * 64;
        // ---- dw loads: 4 consecutive v per lane, per cb-half ----
        s4v dwv[2][4];
#pragma unroll
        for (int cb = 0; cb < 2; ++cb)
#pragma unroll
            for (int vt = 0; vt < 4; ++vt) {
                int vg = vs + vt * 16 + q * 4;
                dwv[cb][vt] = (vg < V_)
                    ? *(const s4v*)(dwbf + (size_t)(b0 + cb * 16 + l16) * V_ + vg)
                    : (s4v)0;
            }
        // ---- phase 1: den [64 v x 32 b], D row=v col=b; A-loads feed 2 cb ----
        f4 acc1[2][4];
#pragma unroll
        for (int cb = 0; cb < 2; ++cb)
#pragma unroll
            for (int vt = 0; vt < 4; ++vt) acc1[cb][vt] = (f4)0.f;
#pragma unroll
        for (int ks = 0; ks < 4; ++ks) {
            int ko = ks * 32 + q * 8;
            s8v bv[4];
#pragma unroll
            for (int vt = 0; vt < 4; ++vt)
                bv[vt] = *(const s8v*)(A1 + (size_t)(vs + vt * 16 + l16) * KP + ko);
#pragma unroll
            for (int cb = 0; cb < 2; ++cb)
#pragma unroll
                for (int vt = 0; vt < 4; ++vt)
                    acc1[cb][vt] = MFMA(bv[vt], au[cb][ks], acc1[cb][vt]);
        }
        // ---- divide + vv -> wave-private LDS [b][v] (one b64 write per cb,vt) ----
#pragma unroll
        for (int cb = 0; cb < 2; ++cb)
#pragma unroll
            for (int vt = 0; vt < 4; ++vt) {
                int vg = vs + vt * 16 + q * 4;
                s4v o;
                if (vg < V_) {
#pragma unroll
                    for (int r = 0; r < 4; ++r)
                        o[r] = f2bf(bf2f(dwv[cb][vt][r]) * __builtin_amdgcn_rcpf(acc1[cb][vt][r]));
                } else {
                    o = (s4v)0;   // den==0 on pads: avoid 0*inf NaN
                }
                *(s4v*)(buf + (cb * 16 + l16) * LDV + vt * 16 + q * 4) = o;
            }
        // ---- phase 2: C2[t][b] += A2 @ vv^T (own LDS; compiler orders RAW) ----
#pragma unroll
        for (int ks2 = 0; ks2 < 2; ++ks2) {
            int ko = ks2 * 32 + q * 8;
            s8v bb[2];
#pragma unroll
            for (int cb = 0; cb < 2; ++cb)
                bb[cb] = *(const s8v*)(buf + (cb * 16 + l16) * LDV + ko);
#pragma unroll
            for (int tt = 0; tt < 7; ++tt) {
                s8v a = *(const s8v*)(A2acc + (size_t)(tt * 16 + l16) * VP + vs + ko);
#pragma unroll
                for (int cb = 0; cb < 2; ++cb)
                    acc2[tt][cb] = MFMA(a, bb[cb], acc2[tt][cb]);
            }
        }
    }
#pragma unroll
    for (int tt = 0; tt < 7; ++tt)
#pragma unroll
        for (int cb = 0; cb < 2; ++cb) {
            int bg = b0 + cb * 16 + l16;
            __builtin_nontemporal_store(acc2[tt][cb],
                (f4*)(part2 + ((size_t)c * B_ + bg) * TP + tt * 16 + q * 4));
        }
}

// reduce partials; mode 0: u = dt/sum -> uf fp32 + uTbf bf16; mode 1: kmvf = sum
__global__ void k_R(const float* __restrict__ part2, const float* __restrict__ dt,
                    float* __restrict__ uf, short* __restrict__ uTbf,
                    float* __restrict__ kmvf, int mode) {
    int id = blockIdx.x * 256 + threadIdx.x;   // < B_*28
    int b = id / 28, t4 = (id % 28) * 4;
    f4 s = (f4)0.f;
    for (int c = 0; c < NC2; ++c)
        s += __builtin_nontemporal_load(
                 (const f4*)(part2 + ((size_t)c * B_ + b) * TP + t4));
    if (mode == 0) {
#pragma unroll
        for (int j = 0; j < 4; ++j) {
            int t = t4 + j;
            float v = (t < T_) ? dt[(size_t)b * T_ + t] / s[j] : 0.f;
            uf[(size_t)b * TP + t] = v;
            uTbf[(size_t)b * KP + t] = f2bf(v);
        }
    } else {
#pragma unroll
        for (int j = 0; j < 4; ++j) kmvf[(size_t)b * TP + t4 + j] = s[j];
    }
}

// rec loss: logits = (1-M)^T-frag @ dt-frag (D row=v col=b); no atomics, no LDS.
//   r6 post-mortem: xv[16]+acc[16] blew the register budget (VGPR 124) so the
//   compiler sank x-loads into the tail where they serialize at HBM latency.
//   Now 128 v per block (xv[8]+acc[8] ~ 100 VGPR): loads genuinely hoist ahead
//   of the MFMA phase, 5056 blocks for supply, launch_bounds(256,4).
__global__ __launch_bounds__(256, 4) void k_rec(const short* __restrict__ dtbf,
                                                const short* __restrict__ W1,
                                                const float* __restrict__ x,
                                                float* __restrict__ recP) {
    int tid = threadIdx.x;
    int wave = tid >> 6, lane = tid & 63, q = lane >> 4, l16 = lane & 15;
    int xb = blockIdx.x;
    int v0 = xb * 128;
    int b0 = blockIdx.y * 64;
    int bg = b0 + wave * 16 + l16;     // this thread's b
    // ---- issue all 8 x loads first: outstanding, covered by MFMA phase ----
    f4 xv[8];
#pragma unroll
    for (int vt = 0; vt < 8; ++vt) {
        int vg = v0 + vt * 16 + q * 4;
        xv[vt] = (vg < V_) ? *(const f4*)(x + (size_t)bg * V_ + vg) : (f4)0.f;
    }
    // B-frags: dt row bg (lane n=l16 -> b)
    s8v a[4];
#pragma unroll
    for (int ks = 0; ks < 4; ++ks)
        a[ks] = *(const s8v*)(dtbf + (size_t)bg * KP + ks * 32 + q * 8);
    f4 acc[8];
#pragma unroll
    for (int vt = 0; vt < 8; ++vt) acc[vt] = (f4)0.f;
#pragma unroll
    for (int ks = 0; ks < 4; ++ks) {
        int ko = ks * 32 + q * 8;
#pragma unroll
        for (int vt = 0; vt < 8; ++vt) {
            s8v w = *(const s8v*)(W1 + (size_t)(v0 + vt * 16 + l16) * KP + ko);
            acc[vt] = MFMA(w, a[ks], acc[vt]);
        }
    }
    // D: row=v (vt*16 + q*4 + r), col=b (l16) -> per lane 4 consecutive v at bg
    float se = 0.f, sxl = 0.f, sx = 0.f;
#pragma unroll
    for (int vt = 0; vt < 8; ++vt) {
        int vg = v0 + vt * 16 + q * 4;
        if (vg < V_) {
#pragma unroll
            for (int r = 0; r < 4; ++r) {
                float lo = acc[vt][r];
                se += __expf(lo); sxl += lo * xv[vt][r]; sx += xv[vt][r];
            }
        }
    }
    // reduce over q (lanes ^16, ^32) -> q==0 lanes hold totals for bg
    se  += __shfl_xor(se, 16, 64);  se  += __shfl_xor(se, 32, 64);
    sxl += __shfl_xor(sxl, 16, 64); sxl += __shfl_xor(sxl, 32, 64);
    sx  += __shfl_xor(sx, 16, 64);  sx  += __shfl_xor(sx, 32, 64);
    if (q == 0) {
        recP[((size_t)xb * 3 + 0) * B_ + bg] = se;
        recP[((size_t)xb * 3 + 1) * B_ + bg] = sxl;
        recP[((size_t)xb * 3 + 2) * B_ + bg] = sx;
    }
}

// divb + reduce rec partials (RXB v-blocks) into recSE/recSXL/recSX
__global__ void k_div(const float* __restrict__ uf, const float* __restrict__ kmvf,
                      const float* __restrict__ recP, float* __restrict__ divb,
                      float* __restrict__ recSE, float* __restrict__ recSXL,
                      float* __restrict__ recSX) {
    int b = blockIdx.x * 256 + threadIdx.x;
    if (b >= B_) return;
    float s = 0.f;
    for (int t = 0; t < TP; ++t) s += uf[(size_t)b * TP + t] * kmvf[(size_t)b * TP + t];
    divb[b] = s;
    float se = 0.f, sxl = 0.f, sx = 0.f;
    for (int xb = 0; xb < RXB; ++xb) {
        se  += recP[((size_t)xb * 3 + 0) * B_ + b];
        sxl += recP[((size_t)xb * 3 + 1) * B_ + b];
        sx  += recP[((size_t)xb * 3 + 2) * B_ + b];
    }
    recSE[b] = se; recSXL[b] = sxl; recSX[b] = sx;
}

__global__ void k_final(const float* __restrict__ divb, const float* __restrict__ recSE,
                        const float* __restrict__ recSXL, const float* __restrict__ recSX,
                        const int* __restrict__ wptr, float* __restrict__ out) {
    __shared__ float sA[256], sB[256];
    int tid = threadIdx.x;
    float accS = 0.f, accR = 0.f;
    for (int b = tid; b < B_; b += 256) {
        accS += divb[b];
        accR += recSXL[b] - logf(recSE[b]) * recSX[b];
    }
    sA[tid] = accS; sB[tid] = accR;
    __syncthreads();
    for (int s = 128; s > 0; s >>= 1) {
        if (tid < s) { sA[tid] += sA[tid + s]; sB[tid] += sB[tid + s]; }
        __syncthreads();
    }
    if (tid == 0) {
        float sh = sA[0] / (float)B_;
        float rec = -sB[0] / (float)B_;
        out[0] = rec;
        out[1] = sh;
        out[2] = (float)(*wptr) * rec + sh;
    }
}

extern "C" void kernel_launch(void* const* d_in, const int* in_sizes, int n_in,
                              void* d_out, int out_size, void* d_ws, size_t ws_size,
                              hipStream_t stream) {
    const float* x  = (const float*)d_in[0];
    const float* dt = (const float*)d_in[1];
    const float* dw = (const float*)d_in[2];
    const float* M  = (const float*)d_in[3];
    const int* alpha = (const int*)d_in[5];
    const int* wrec  = (const int*)d_in[6];
    float* out = (float*)d_out;

    char* p = (char*)d_ws;
    short* A1   = (short*)p; p += (size_t)VP * KP * 2;
    short* W1   = (short*)p; p += (size_t)VP * KP * 2;
    short* A2   = (short*)p; p += (size_t)TP * VP * 2;
    short* A2M  = (short*)p; p += (size_t)TP * VP * 2;
    short* uTbf = (short*)p; p += (size_t)B_ * KP * 2;
    short* dtbf = (short*)p; p += (size_t)B_ * KP * 2;
    short* dwbf = (short*)p; p += (size_t)B_ * V_ * 2;
    float* part2 = (float*)p; p += (size_t)NC2 * B_ * TP * 4;
    float* uf    = (float*)p; p += (size_t)B_ * TP * 4;
    float* kmvf  = (float*)p; p += (size_t)B_ * TP * 4;
    float* recP  = (float*)p; p += (size_t)RXB * 3 * B_ * 4;
    float* recSE  = (float*)p; p += B_ * 4;
    float* recSXL = (float*)p; p += B_ * 4;
    float* recSX  = (float*)p; p += B_ * 4;
    float* divb   = (float*)p; p += B_ * 4;

    k_initKT<<<dim3(VP / 32, 4), dim3(32, 8), 0, stream>>>(M, alpha, A1, W1);
    k_initA2<<<(TP * VP) / 256, 256, 0, stream>>>(M, alpha, A2, A2M);
    k_init0<<<(B_ * KP) / 256, 256, 0, stream>>>(uTbf);
    k_castdw<<<(B_ * V_) / (256 * 8), 256, 0, stream>>>(dw, dwbf);
    k_castdt<<<(B_ * KP) / 256, 256, 0, stream>>>(dt, dtbf);
    k_rec<<<dim3(RXB, B_ / 64), 256, 0, stream>>>(dtbf, W1, x, recP);

    for (int it = 0; it < 50; ++it) {
        k_GF<<<dim3((B_ / 128) * NC2), 256, 0, stream>>>(A1, A2, uTbf, dwbf, part2);
        k_R<<<(B_ * 28) / 256, 256, 0, stream>>>(part2, dt, uf, uTbf, kmvf, 0);
    }
    k_GF<<<dim3((B_ / 128) * NC2), 256, 0, stream>>>(A1, A2M, uTbf, dwbf, part2);
    k_R<<<(B_ * 28) / 256, 256, 0, stream>>>(part2, dt, uf, uTbf, kmvf, 1);
    k_div<<<B_ / 256, 256, 0, stream>>>(uf, kmvf, recP, divb, recSE, recSXL, recSX);
    k_final<<<1, 256, 0, stream>>>(divb, recSE, recSXL, recSX, wrec, out);
}

// Round 9
// 4975.706 us; speedup vs baseline: 1.3645x; 1.3645x over previous
//
#include <hip/hip_runtime.h>
#include <math.h>

#define B_   2048
#define T_   100
#define V_   20000
#define VP   20480
#define KP   128
#define TP   112
#define NC2  32
#define CH2  640
#define LDV  72    // vv LDS row stride (shorts): 144B = 16B-aligned, 2-way banks (free)
#define RXB  158   // k_rec v-split blocks (128 v each)

typedef short s8v __attribute__((ext_vector_type(8)));
typedef short s4v __attribute__((ext_vector_type(4)));
typedef float f4  __attribute__((ext_vector_type(4)));

__device__ __forceinline__ short f2bf(float f) {
    unsigned u = __builtin_bit_cast(unsigned, f);
    u += 0x7fffu + ((u >> 16) & 1u);
    return (short)(u >> 16);
}
__device__ __forceinline__ float bf2f(short h) {
    unsigned u = ((unsigned)(unsigned short)h) << 16;
    return __builtin_bit_cast(float, u);
}
#define MFMA(a,b,c) __builtin_amdgcn_mfma_f32_16x16x32_bf16((a),(b),(c),0,0,0)

// A1[v][t] = exp(-lam*M[t][v]) bf16 (t-pad to 128, v-pad to VP, zeros)
// W1[v][t] = 1 - M[t][v] bf16 (same pads)
__global__ void k_initKT(const float* __restrict__ M, const int* __restrict__ alpha,
                         short* __restrict__ A1, short* __restrict__ W1) {
    __shared__ float tile[32][33];
    float lam = (float)(*alpha);
    int v0 = blockIdx.x * 32, t0 = blockIdx.y * 32;
    int tx = threadIdx.x, ty = threadIdx.y;
    for (int j = 0; j < 4; ++j) {
        int t = t0 + ty + 8 * j, v = v0 + tx;
        tile[ty + 8 * j][tx] = (t < T_ && v < V_) ? M[(size_t)t * V_ + v] : 0.f;
    }
    __syncthreads();
    for (int j = 0; j < 4; ++j) {
        int t = t0 + tx, v = v0 + ty + 8 * j;
        float m = tile[tx][ty + 8 * j];
        bool valid = (t < T_) && (v < V_);
        A1[(size_t)v * KP + t] = valid ? f2bf(__expf(-m * lam)) : (short)0;
        W1[(size_t)v * KP + t] = valid ? f2bf(1.f - m) : (short)0;
    }
}

// A2[t][v] = K bf16, A2M[t][v] = K*M bf16; [TP][VP] zero-padded
__global__ void k_initA2(const float* __restrict__ M, const int* __restrict__ alpha,
                         short* __restrict__ A2, short* __restrict__ A2M) {
    float lam = (float)(*alpha);
    size_t id = (size_t)blockIdx.x * 256 + threadIdx.x;   // < TP*VP
    int t = (int)(id / VP), v = (int)(id % VP);
    bool valid = (t < T_) && (v < V_);
    float m = valid ? M[(size_t)t * V_ + v] : 0.f;
    float k = valid ? __expf(-m * lam) : 0.f;
    A2[id]  = valid ? f2bf(k) : (short)0;
    A2M[id] = valid ? f2bf(k * m) : (short)0;
}

// uT init (1/T in bf16, pads zero)
__global__ void k_init0(short* __restrict__ uTbf) {
    int id = blockIdx.x * 256 + threadIdx.x;   // < B_*KP
    int t = id & (KP - 1);
    uTbf[id] = (t < T_) ? f2bf(0.01f) : (short)0;
}

// dwbf[b][v] = bf16(dw[b][v]) flat; nt (one-shot fp32 stream)
__global__ void k_castdw(const float* __restrict__ dw, short* __restrict__ dwbf) {
    size_t base = ((size_t)blockIdx.x * 256 + threadIdx.x) * 8;   // < B_*V_
    f4 x0 = __builtin_nontemporal_load((const f4*)(dw + base));
    f4 x1 = __builtin_nontemporal_load((const f4*)(dw + base + 4));
    s8v o;
    o[0]=f2bf(x0[0]); o[1]=f2bf(x0[1]); o[2]=f2bf(x0[2]); o[3]=f2bf(x0[3]);
    o[4]=f2bf(x1[0]); o[5]=f2bf(x1[1]); o[6]=f2bf(x1[2]); o[7]=f2bf(x1[3]);
    __builtin_nontemporal_store(o, (s8v*)(dwbf + base));
}

// dtbf[b][t] bf16, t-pad 128
__global__ void k_castdt(const float* __restrict__ dt, short* __restrict__ dtbf) {
    int id = blockIdx.x * 256 + threadIdx.x;   // < B_*KP
    int b = id >> 7, t = id & (KP - 1);
    dtbf[id] = (t < T_) ? f2bf(dt[(size_t)b * T_ + t]) : (short)0;
}

// Fused Sinkhorn iteration kernel — r8 reverted to the proven r4/r6 shape
// (NC2=32, 640-v chunks, 10 strips, LB(256,2), free-running, plain part2),
// plus ONE new lever: strip-parity DOUBLE-BUFFERED wave-private LDS and
// #pragma unroll 2 on the strip loop. Previously the single LDS buffer forced
// phase2(s) to drain before phase1(s+1) could write -> one dependency chain.
// With parity buffers, strips s,s+1 are fully independent: the scheduler can
// issue strip s+1's ~38 global loads while strip s's phase-2 waits, doubling
// the per-wave outstanding-load window (the latency-bound kernel's limiter).
__global__ __launch_bounds__(256, 2) void k_GF(const short* __restrict__ A1,
                                               const short* __restrict__ A2acc,
                                               const short* __restrict__ uT,
                                               const short* __restrict__ dwbf,
                                               float* __restrict__ part2) {
    __shared__ short vv[4][2][32 * LDV];   // [wave][strip parity][b-row][v]
    int tid = threadIdx.x;
    int wave = tid >> 6, lane = tid & 63, q = lane >> 4, l16 = lane & 15;

    // bijective swizzle: linear id l -> (bx, c) with XCD (l%8) -> chunks 4x..4x+3
    int l = blockIdx.x;
    int j = l & 31, bx = l >> 5;
    int c = ((j & 7) << 2) | (j >> 3);
    int v0 = c * CH2;
    int b0 = bx * 128 + wave * 32;     // wave's 32 b

    // hoisted uT B-frags (lane n=l16 -> b; k = ks*32 + q*8 + j), strip-invariant
    s8v au[2][4];
#pragma unroll
    for (int cb = 0; cb < 2; ++cb)
#pragma unroll
        for (int ks = 0; ks < 4; ++ks)
            au[cb][ks] = *(const s8v*)(uT + (size_t)(b0 + cb * 16 + l16) * KP + ks * 32 + q * 8);

    f4 acc2[7][2];
#pragma unroll
    for (int tt = 0; tt < 7; ++tt) { acc2[tt][0] = (f4)0.f; acc2[tt][1] = (f4)0.f; }

#pragma unroll 2
    for (int s = 0; s < 10; ++s) {
        int vs = v0 + s * 64;
        short* buf = vv[wave][s & 1];  // parity double-buffer (compile-time after unroll)
        // ---- dw loads: 4 consecutive v per lane, per cb-half ----
        s4v dwv[2][4];
#pragma unroll
        for (int cb = 0; cb < 2; ++cb)
#pragma unroll
            for (int vt = 0; vt < 4; ++vt) {
                int vg = vs + vt * 16 + q * 4;
                dwv[cb][vt] = (vg < V_)
                    ? *(const s4v*)(dwbf + (size_t)(b0 + cb * 16 + l16) * V_ + vg)
                    : (s4v)0;
            }
        // ---- phase 1: den [64 v x 32 b], D row=v col=b; A-loads feed 2 cb ----
        f4 acc1[2][4];
#pragma unroll
        for (int cb = 0; cb < 2; ++cb)
#pragma unroll
            for (int vt = 0; vt < 4; ++vt) acc1[cb][vt] = (f4)0.f;
#pragma unroll
        for (int ks = 0; ks < 4; ++ks) {
            int ko = ks * 32 + q * 8;
            s8v bv[4];
#pragma unroll
            for (int vt = 0; vt < 4; ++vt)
                bv[vt] = *(const s8v*)(A1 + (size_t)(vs + vt * 16 + l16) * KP + ko);
#pragma unroll
            for (int cb = 0; cb < 2; ++cb)
#pragma unroll
                for (int vt = 0; vt < 4; ++vt)
                    acc1[cb][vt] = MFMA(bv[vt], au[cb][ks], acc1[cb][vt]);
        }
        // ---- divide + vv -> wave-private LDS [b][v] (one b64 write per cb,vt) ----
#pragma unroll
        for (int cb = 0; cb < 2; ++cb)
#pragma unroll
            for (int vt = 0; vt < 4; ++vt) {
                int vg = vs + vt * 16 + q * 4;
                s4v o;
                if (vg < V_) {
#pragma unroll
                    for (int r = 0; r < 4; ++r)
                        o[r] = f2bf(bf2f(dwv[cb][vt][r]) * __builtin_amdgcn_rcpf(acc1[cb][vt][r]));
                } else {
                    o = (s4v)0;   // den==0 on pads: avoid 0*inf NaN
                }
                *(s4v*)(buf + (cb * 16 + l16) * LDV + vt * 16 + q * 4) = o;
            }
        // ---- phase 2: C2[t][b] += A2 @ vv^T (own LDS; compiler orders RAW) ----
#pragma unroll
        for (int ks2 = 0; ks2 < 2; ++ks2) {
            int ko = ks2 * 32 + q * 8;
            s8v bb[2];
#pragma unroll
            for (int cb = 0; cb < 2; ++cb)
                bb[cb] = *(const s8v*)(buf + (cb * 16 + l16) * LDV + ko);
#pragma unroll
            for (int tt = 0; tt < 7; ++tt) {
                s8v a = *(const s8v*)(A2acc + (size_t)(tt * 16 + l16) * VP + vs + ko);
#pragma unroll
                for (int cb = 0; cb < 2; ++cb)
                    acc2[tt][cb] = MFMA(a, bb[cb], acc2[tt][cb]);
            }
        }
    }
#pragma unroll
    for (int tt = 0; tt < 7; ++tt)
#pragma unroll
        for (int cb = 0; cb < 2; ++cb) {
            int bg = b0 + cb * 16 + l16;
            *(f4*)(part2 + ((size_t)c * B_ + bg) * TP + tt * 16 + q * 4) = acc2[tt][cb];
        }
}

// reduce partials; mode 0: u = dt/sum -> uf fp32 + uTbf bf16; mode 1: kmvf = sum
__global__ void k_R(const float* __restrict__ part2, const float* __restrict__ dt,
                    float* __restrict__ uf, short* __restrict__ uTbf,
                    float* __restrict__ kmvf, int mode) {
    int id = blockIdx.x * 256 + threadIdx.x;   // < B_*28
    int b = id / 28, t4 = (id % 28) * 4;
    f4 s = (f4)0.f;
    for (int c = 0; c < NC2; ++c)
        s += *(const f4*)(part2 + ((size_t)c * B_ + b) * TP + t4);
    if (mode == 0) {
#pragma unroll
        for (int j = 0; j < 4; ++j) {
            int t = t4 + j;
            float v = (t < T_) ? dt[(size_t)b * T_ + t] / s[j] : 0.f;
            uf[(size_t)b * TP + t] = v;
            uTbf[(size_t)b * KP + t] = f2bf(v);
        }
    } else {
#pragma unroll
        for (int j = 0; j < 4; ++j) kmvf[(size_t)b * TP + t4 + j] = s[j];
    }
}

// rec loss: logits = (1-M)^T-frag @ dt-frag (D row=v col=b); no atomics, no LDS.
//   128 v per block (xv[8]+acc[8] fit the budget): x-loads genuinely hoist
//   ahead of the MFMA phase, 5056 blocks for supply, launch_bounds(256,4).
__global__ __launch_bounds__(256, 4) void k_rec(const short* __restrict__ dtbf,
                                                const short* __restrict__ W1,
                                                const float* __restrict__ x,
                                                float* __restrict__ recP) {
    int tid = threadIdx.x;
    int wave = tid >> 6, lane = tid & 63, q = lane >> 4, l16 = lane & 15;
    int xb = blockIdx.x;
    int v0 = xb * 128;
    int b0 = blockIdx.y * 64;
    int bg = b0 + wave * 16 + l16;     // this thread's b
    // ---- issue all 8 x loads first: outstanding, covered by MFMA phase ----
    f4 xv[8];
#pragma unroll
    for (int vt = 0; vt < 8; ++vt) {
        int vg = v0 + vt * 16 + q * 4;
        xv[vt] = (vg < V_) ? *(const f4*)(x + (size_t)bg * V_ + vg) : (f4)0.f;
    }
    // B-frags: dt row bg (lane n=l16 -> b)
    s8v a[4];
#pragma unroll
    for (int ks = 0; ks < 4; ++ks)
        a[ks] = *(const s8v*)(dtbf + (size_t)bg * KP + ks * 32 + q * 8);
    f4 acc[8];
#pragma unroll
    for (int vt = 0; vt < 8; ++vt) acc[vt] = (f4)0.f;
#pragma unroll
    for (int ks = 0; ks < 4; ++ks) {
        int ko = ks * 32 + q * 8;
#pragma unroll
        for (int vt = 0; vt < 8; ++vt) {
            s8v w = *(const s8v*)(W1 + (size_t)(v0 + vt * 16 + l16) * KP + ko);
            acc[vt] = MFMA(w, a[ks], acc[vt]);
        }
    }
    // D: row=v (vt*16 + q*4 + r), col=b (l16) -> per lane 4 consecutive v at bg
    float se = 0.f, sxl = 0.f, sx = 0.f;
#pragma unroll
    for (int vt = 0; vt < 8; ++vt) {
        int vg = v0 + vt * 16 + q * 4;
        if (vg < V_) {
#pragma unroll
            for (int r = 0; r < 4; ++r) {
                float lo = acc[vt][r];
                se += __expf(lo); sxl += lo * xv[vt][r]; sx += xv[vt][r];
            }
        }
    }
    // reduce over q (lanes ^16, ^32) -> q==0 lanes hold totals for bg
    se  += __shfl_xor(se, 16, 64);  se  += __shfl_xor(se, 32, 64);
    sxl += __shfl_xor(sxl, 16, 64); sxl += __shfl_xor(sxl, 32, 64);
    sx  += __shfl_xor(sx, 16, 64);  sx  += __shfl_xor(sx, 32, 64);
    if (q == 0) {
        recP[((size_t)xb * 3 + 0) * B_ + bg] = se;
        recP[((size_t)xb * 3 + 1) * B_ + bg] = sxl;
        recP[((size_t)xb * 3 + 2) * B_ + bg] = sx;
    }
}

// divb + reduce rec partials (RXB v-blocks) into recSE/recSXL/recSX
__global__ void k_div(const float* __restrict__ uf, const float* __restrict__ kmvf,
                      const float* __restrict__ recP, float* __restrict__ divb,
                      float* __restrict__ recSE, float* __restrict__ recSXL,
                      float* __restrict__ recSX) {
    int b = blockIdx.x * 256 + threadIdx.x;
    if (b >= B_) return;
    float s = 0.f;
    for (int t = 0; t < TP; ++t) s += uf[(size_t)b * TP + t] * kmvf[(size_t)b * TP + t];
    divb[b] = s;
    float se = 0.f, sxl = 0.f, sx = 0.f;
    for (int xb = 0; xb < RXB; ++xb) {
        se  += recP[((size_t)xb * 3 + 0) * B_ + b];
        sxl += recP[((size_t)xb * 3 + 1) * B_ + b];
        sx  += recP[((size_t)xb * 3 + 2) * B_ + b];
    }
    recSE[b] = se; recSXL[b] = sxl; recSX[b] = sx;
}

__global__ void k_final(const float* __restrict__ divb, const float* __restrict__ recSE,
                        const float* __restrict__ recSXL, const float* __restrict__ recSX,
                        const int* __restrict__ wptr, float* __restrict__ out) {
    __shared__ float sA[256], sB[256];
    int tid = threadIdx.x;
    float accS = 0.f, accR = 0.f;
    for (int b = tid; b < B_; b += 256) {
        accS += divb[b];
        accR += recSXL[b] - logf(recSE[b]) * recSX[b];
    }
    sA[tid] = accS; sB[tid] = accR;
    __syncthreads();
    for (int s = 128; s > 0; s >>= 1) {
        if (tid < s) { sA[tid] += sA[tid + s]; sB[tid] += sB[tid + s]; }
        __syncthreads();
    }
    if (tid == 0) {
        float sh = sA[0] / (float)B_;
        float rec = -sB[0] / (float)B_;
        out[0] = rec;
        out[1] = sh;
        out[2] = (float)(*wptr) * rec + sh;
    }
}

extern "C" void kernel_launch(void* const* d_in, const int* in_sizes, int n_in,
                              void* d_out, int out_size, void* d_ws, size_t ws_size,
                              hipStream_t stream) {
    const float* x  = (const float*)d_in[0];
    const float* dt = (const float*)d_in[1];
    const float* dw = (const float*)d_in[2];
    const float* M  = (const float*)d_in[3];
    const int* alpha = (const int*)d_in[5];
    const int* wrec  = (const int*)d_in[6];
    float* out = (float*)d_out;

    char* p = (char*)d_ws;
    short* A1   = (short*)p; p += (size_t)VP * KP * 2;
    short* W1   = (short*)p; p += (size_t)VP * KP * 2;
    short* A2   = (short*)p; p += (size_t)TP * VP * 2;
    short* A2M  = (short*)p; p += (size_t)TP * VP * 2;
    short* uTbf = (short*)p; p += (size_t)B_ * KP * 2;
    short* dtbf = (short*)p; p += (size_t)B_ * KP * 2;
    short* dwbf = (short*)p; p += (size_t)B_ * V_ * 2;
    float* part2 = (float*)p; p += (size_t)NC2 * B_ * TP * 4;
    float* uf    = (float*)p; p += (size_t)B_ * TP * 4;
    float* kmvf  = (float*)p; p += (size_t)B_ * TP * 4;
    float* recP  = (float*)p; p += (size_t)RXB * 3 * B_ * 4;
    float* recSE  = (float*)p; p += B_ * 4;
    float* recSXL = (float*)p; p += B_ * 4;
    float* recSX  = (float*)p; p += B_ * 4;
    float* divb   = (float*)p; p += B_ * 4;

    k_initKT<<<dim3(VP / 32, 4), dim3(32, 8), 0, stream>>>(M, alpha, A1, W1);
    k_initA2<<<(TP * VP) / 256, 256, 0, stream>>>(M, alpha, A2, A2M);
    k_init0<<<(B_ * KP) / 256, 256, 0, stream>>>(uTbf);
    k_castdw<<<(B_ * V_) / (256 * 8), 256, 0, stream>>>(dw, dwbf);
    k_castdt<<<(B_ * KP) / 256, 256, 0, stream>>>(dt, dtbf);
    k_rec<<<dim3(RXB, B_ / 64), 256, 0, stream>>>(dtbf, W1, x, recP);

    for (int it = 0; it < 50; ++it) {
        k_GF<<<dim3((B_ / 128) * NC2), 256, 0, stream>>>(A1, A2, uTbf, dwbf, part2);
        k_R<<<(B_ * 28) / 256, 256, 0, stream>>>(part2, dt, uf, uTbf, kmvf, 0);
    }
    k_GF<<<dim3((B_ / 128) * NC2), 256, 0, stream>>>(A1, A2M, uTbf, dwbf, part2);
    k_R<<<(B_ * 28) / 256, 256, 0, stream>>>(part2, dt, uf, uTbf, kmvf, 1);
    k_div<<<B_ / 256, 256, 0, stream>>>(uf, kmvf, recP, divb, recSE, recSXL, recSX);
    k_final<<<1, 256, 0, stream>>>(divb, recSE, recSXL, recSX, wrec, out);
}